// Round 1
// baseline (793.687 us; speedup 1.0000x reference)
//
#include <hip/hip_runtime.h>

// Problem constants (match reference)
#define N_NODES_C 100000
#define D_FEAT_C 16

// q = pred - input, vectorized float4 over N*16 floats
__global__ void k_q(const float* __restrict__ pred, const float* __restrict__ inp,
                    float* __restrict__ q, int n4) {
    int i = blockIdx.x * blockDim.x + threadIdx.x;
    if (i < n4) {
        float4 a = reinterpret_cast<const float4*>(pred)[i];
        float4 b = reinterpret_cast<const float4*>(inp)[i];
        float4 r;
        r.x = a.x - b.x; r.y = a.y - b.y; r.z = a.z - b.z; r.w = a.w - b.w;
        reinterpret_cast<float4*>(q)[i] = r;
    }
}

// One quad of lanes (4 lanes) per edge; each lane handles 4 features.
// sums[row] += q[row] - q[col]  (16 floats), cnt[row] += 1
__global__ void k_scatter(const int* __restrict__ row, const int* __restrict__ col,
                          const float4* __restrict__ q4, float* __restrict__ sums,
                          unsigned int* __restrict__ cnt, int E) {
    long long t = (long long)blockIdx.x * blockDim.x + threadIdx.x;
    int e = (int)(t >> 2);
    int p = (int)(t & 3);
    if (e >= E) return;
    int r = row[e];
    int c = col[e];
    float4 a = q4[(long long)r * 4 + p];
    float4 b = q4[(long long)c * 4 + p];
    float* s = sums + (long long)r * 16 + p * 4;
    atomicAdd(s + 0, a.x - b.x);
    atomicAdd(s + 1, a.y - b.y);
    atomicAdd(s + 2, a.z - b.z);
    atomicAdd(s + 3, a.w - b.w);
    if (p == 0) atomicAdd(cnt + r, 1u);
}

// Per node: ||sums||^2 / max(cnt,1)^2, averaged over nodes into out[0]
__global__ void k_finish(const float* __restrict__ sums, const unsigned int* __restrict__ cnt,
                         float* __restrict__ out, int n) {
    int i = blockIdx.x * blockDim.x + threadIdx.x;
    float contrib = 0.0f;
    if (i < n) {
        unsigned int cu = cnt[i];
        float c = (float)(cu > 1u ? cu : 1u);
        const float4* s4 = reinterpret_cast<const float4*>(sums + (long long)i * 16);
        float ss = 0.0f;
        #pragma unroll
        for (int k = 0; k < 4; ++k) {
            float4 v = s4[k];
            ss += v.x * v.x + v.y * v.y + v.z * v.z + v.w * v.w;
        }
        contrib = ss / (c * c) * (1.0f / (float)N_NODES_C);
    }
    // wave(64) reduce
    #pragma unroll
    for (int off = 32; off > 0; off >>= 1)
        contrib += __shfl_down(contrib, off);
    if ((threadIdx.x & 63) == 0)
        atomicAdd(out, contrib);
}

extern "C" void kernel_launch(void* const* d_in, const int* in_sizes, int n_in,
                              void* d_out, int out_size, void* d_ws, size_t ws_size,
                              hipStream_t stream) {
    const float* pred = (const float*)d_in[0];
    const float* inp  = (const float*)d_in[1];
    const int*   eidx = (const int*)d_in[2];

    const int N = N_NODES_C;
    const int E = in_sizes[2] / 2;

    const int* row = eidx;
    const int* col = eidx + E;

    // ws layout: sums [N*16 f32] | cnt [N u32] | q [N*16 f32]
    float*        sums = (float*)d_ws;
    unsigned int* cnt  = (unsigned int*)((char*)d_ws + (size_t)N * 16 * sizeof(float));
    float*        q    = (float*)((char*)d_ws + (size_t)N * 16 * sizeof(float) + (size_t)N * sizeof(unsigned int));

    // zero sums + cnt (contiguous), and the scalar output
    hipMemsetAsync(d_ws, 0, (size_t)N * 16 * sizeof(float) + (size_t)N * sizeof(unsigned int), stream);
    hipMemsetAsync(d_out, 0, sizeof(float), stream);

    // q = pred - input
    int n4 = N * D_FEAT_C / 4;
    int blkq = (n4 + 255) / 256;
    k_q<<<blkq, 256, 0, stream>>>(pred, inp, q, n4);

    // edge scatter: 4 lanes per edge
    long long tot = (long long)E * 4;
    int blks = (int)((tot + 255) / 256);
    k_scatter<<<blks, 256, 0, stream>>>(row, col, (const float4*)q, sums, cnt, E);

    // finish: per-node norm / count^2, mean into out
    int blkf = (N + 255) / 256;
    k_finish<<<blkf, 256, 0, stream>>>(sums, cnt, (float*)d_out, N);
}

// Round 2
// 499.664 us; speedup vs baseline: 1.5884x; 1.5884x over previous
//
#include <hip/hip_runtime.h>

#define NN 100000
#define DF 16
#define SCAN_BLK 256

// q = pred - input (float4 over N*16)
__global__ void k_q(const float4* __restrict__ pred, const float4* __restrict__ inp,
                    float4* __restrict__ q, int n4) {
    int i = blockIdx.x * blockDim.x + threadIdx.x;
    if (i < n4) {
        float4 a = pred[i], b = inp[i];
        float4 r; r.x = a.x - b.x; r.y = a.y - b.y; r.z = a.z - b.z; r.w = a.w - b.w;
        q[i] = r;
    }
}

// counts[row[e]]++
__global__ void k_hist(const int* __restrict__ row, unsigned int* __restrict__ counts, int E) {
    int stride = gridDim.x * blockDim.x;
    for (int e = blockIdx.x * blockDim.x + threadIdx.x; e < E; e += stride)
        atomicAdd(&counts[row[e]], 1u);
}

// per-block inclusive scan -> exclusive partials + block totals
__global__ void k_scan1(const unsigned int* __restrict__ counts, unsigned int* __restrict__ part,
                        unsigned int* __restrict__ totals, int n) {
    __shared__ unsigned int s[SCAN_BLK];
    int tid = threadIdx.x;
    int i = blockIdx.x * SCAN_BLK + tid;
    unsigned int v = (i < n) ? counts[i] : 0u;
    s[tid] = v; __syncthreads();
    for (int off = 1; off < SCAN_BLK; off <<= 1) {
        unsigned int t = (tid >= off) ? s[tid - off] : 0u;
        __syncthreads();
        s[tid] += t;
        __syncthreads();
    }
    if (i < n) part[i] = s[tid] - v;          // exclusive within block
    if (tid == SCAN_BLK - 1) totals[blockIdx.x] = s[tid];
}

// single-block exclusive scan of block totals (nb <= 512), in place
__global__ void k_scan2(unsigned int* __restrict__ totals, int nb) {
    __shared__ unsigned int s[512];
    int tid = threadIdx.x;
    unsigned int v = (tid < nb) ? totals[tid] : 0u;
    s[tid] = v; __syncthreads();
    for (int off = 1; off < 512; off <<= 1) {
        unsigned int t = (tid >= off) ? s[tid - off] : 0u;
        __syncthreads();
        s[tid] += t;
        __syncthreads();
    }
    if (tid < nb) totals[tid] = s[tid] - v;   // exclusive
}

// starts[i] = cursor[i] = part[i] + totals[block]
__global__ void k_scan3(const unsigned int* __restrict__ part, const unsigned int* __restrict__ totals,
                        unsigned int* __restrict__ starts, unsigned int* __restrict__ cursor, int n) {
    int i = blockIdx.x * SCAN_BLK + threadIdx.x;
    if (i < n) {
        unsigned int v = part[i] + totals[blockIdx.x];
        starts[i] = v;
        cursor[i] = v;
    }
}

// sorted_col[ cursor[row[e]]++ ] = col[e]
__global__ void k_scatter_idx(const int* __restrict__ row, const int* __restrict__ col,
                              unsigned int* __restrict__ cursor, int* __restrict__ sorted_col, int E) {
    int stride = gridDim.x * blockDim.x;
    for (int e = blockIdx.x * blockDim.x + threadIdx.x; e < E; e += stride) {
        int r = row[e];
        unsigned int pos = atomicAdd(&cursor[r], 1u);
        sorted_col[pos] = col[e];
    }
}

// one wave per node: s = cnt*q[n] - sum_e q[col_e]; node_ss[n] = ||s||^2 / max(cnt,1)^2
__global__ void k_node(const float4* __restrict__ q4, const int* __restrict__ sorted_col,
                       const unsigned int* __restrict__ starts, const unsigned int* __restrict__ counts,
                       float* __restrict__ node_ss, int n) {
    int wave = (blockIdx.x * blockDim.x + threadIdx.x) >> 6;
    int lane = threadIdx.x & 63;
    int p = lane & 3;        // feature quad
    int slot = lane >> 2;    // edge slot 0..15
    if (wave >= n) return;
    unsigned int start = starts[wave];
    unsigned int cnt = counts[wave];
    float4 acc = make_float4(0.f, 0.f, 0.f, 0.f);
    for (unsigned int b = 0; b < cnt; b += 16) {
        unsigned int idx = b + slot;
        if (idx < cnt) {
            int c = sorted_col[start + idx];
            float4 v = q4[(size_t)c * 4 + p];
            acc.x += v.x; acc.y += v.y; acc.z += v.z; acc.w += v.w;
        }
    }
    // reduce across the 16 slots (lanes with same p)
    #pragma unroll
    for (int m = 4; m < 64; m <<= 1) {
        acc.x += __shfl_xor(acc.x, m);
        acc.y += __shfl_xor(acc.y, m);
        acc.z += __shfl_xor(acc.z, m);
        acc.w += __shfl_xor(acc.w, m);
    }
    float4 qn = q4[(size_t)wave * 4 + p];
    float cf = (float)cnt;
    float sx = cf * qn.x - acc.x;
    float sy = cf * qn.y - acc.y;
    float sz = cf * qn.z - acc.z;
    float sw = cf * qn.w - acc.w;
    float ss = sx * sx + sy * sy + sz * sz + sw * sw;
    ss += __shfl_xor(ss, 1);
    ss += __shfl_xor(ss, 2);
    if (lane == 0) {
        float c1 = (float)(cnt > 1u ? cnt : 1u);
        node_ss[wave] = ss / (c1 * c1);
    }
}

// mean over node_ss into out[0]
__global__ void k_reduce(const float* __restrict__ node_ss, float* __restrict__ out, int n) {
    int stride = gridDim.x * blockDim.x;
    float acc = 0.f;
    for (int i = blockIdx.x * blockDim.x + threadIdx.x; i < n; i += stride)
        acc += node_ss[i];
    #pragma unroll
    for (int m = 1; m < 64; m <<= 1)
        acc += __shfl_xor(acc, m);
    if ((threadIdx.x & 63) == 0)
        atomicAdd(out, acc * (1.0f / (float)NN));
}

extern "C" void kernel_launch(void* const* d_in, const int* in_sizes, int n_in,
                              void* d_out, int out_size, void* d_ws, size_t ws_size,
                              hipStream_t stream) {
    const float* pred = (const float*)d_in[0];
    const float* inp  = (const float*)d_in[1];
    const int*   eidx = (const int*)d_in[2];

    const int N = NN;
    const int E = in_sizes[2] / 2;
    const int* row = eidx;
    const int* col = eidx + E;
    const int NB = (N + SCAN_BLK - 1) / SCAN_BLK;   // 391 <= 512

    // ws layout (aligned chunks)
    size_t off = 0;
    auto alloc = [&](size_t bytes) { void* p = (char*)d_ws + off; off = (off + bytes + 511) & ~(size_t)511; return p; };
    float4*       q4         = (float4*)alloc((size_t)N * 16 * sizeof(float));
    unsigned int* counts     = (unsigned int*)alloc((size_t)N * sizeof(unsigned int));
    unsigned int* part       = (unsigned int*)alloc((size_t)N * sizeof(unsigned int));
    unsigned int* totals     = (unsigned int*)alloc(4096);
    unsigned int* starts     = (unsigned int*)alloc((size_t)N * sizeof(unsigned int));
    unsigned int* cursor     = (unsigned int*)alloc((size_t)N * sizeof(unsigned int));
    int*          sorted_col = (int*)alloc((size_t)E * sizeof(int));
    float*        node_ss    = (float*)alloc((size_t)N * sizeof(float));

    hipMemsetAsync(counts, 0, (size_t)N * sizeof(unsigned int), stream);
    hipMemsetAsync(d_out, 0, sizeof(float), stream);

    int n4 = N * DF / 4;
    k_q<<<(n4 + 255) / 256, 256, 0, stream>>>((const float4*)pred, (const float4*)inp, q4, n4);

    k_hist<<<2048, 256, 0, stream>>>(row, counts, E);

    k_scan1<<<NB, SCAN_BLK, 0, stream>>>(counts, part, totals, N);
    k_scan2<<<1, 512, 0, stream>>>(totals, NB);
    k_scan3<<<NB, SCAN_BLK, 0, stream>>>(part, totals, starts, cursor, N);

    k_scatter_idx<<<2048, 256, 0, stream>>>(row, col, cursor, sorted_col, E);

    // one wave per node, 4 waves per block
    int nwaves_blocks = (N + 3) / 4;
    k_node<<<nwaves_blocks, 256, 0, stream>>>(q4, sorted_col, starts, counts, node_ss, N);

    k_reduce<<<256, 256, 0, stream>>>(node_ss, (float*)d_out, N);
}

// Round 3
// 420.175 us; speedup vs baseline: 1.8889x; 1.1892x over previous
//
#include <hip/hip_runtime.h>

#define NN 100000
#define DF 16
#define NBUCK 391      // ceil(100000/256)
#define TPB 256
#define EPT 32
#define TILE (TPB*EPT) // 8192

// q = pred - input (float4 over N*16)
__global__ void k_q(const float4* __restrict__ pred, const float4* __restrict__ inp,
                    float4* __restrict__ q, int n4) {
    int i = blockIdx.x * blockDim.x + threadIdx.x;
    if (i < n4) {
        float4 a = pred[i], b = inp[i];
        float4 r; r.x = a.x - b.x; r.y = a.y - b.y; r.z = a.z - b.z; r.w = a.w - b.w;
        q[i] = r;
    }
}

// LDS-aggregated histogram of bucket = row >> 8
__global__ void k_bhist(const int* __restrict__ row, unsigned int* __restrict__ bcount, int E) {
    __shared__ unsigned int h[NBUCK];
    for (int i = threadIdx.x; i < NBUCK; i += blockDim.x) h[i] = 0u;
    __syncthreads();
    int stride = gridDim.x * blockDim.x;
    for (int e = blockIdx.x * blockDim.x + threadIdx.x; e < E; e += stride)
        atomicAdd(&h[((unsigned int)row[e]) >> 8], 1u);
    __syncthreads();
    for (int i = threadIdx.x; i < NBUCK; i += blockDim.x) {
        unsigned int v = h[i];
        if (v) atomicAdd(&bcount[i], v);
    }
}

// single-block exclusive scan of bucket counts -> bstart, cursor
__global__ void k_bscan(const unsigned int* __restrict__ bcount,
                        unsigned int* __restrict__ bstart,
                        unsigned int* __restrict__ cursor, int nb) {
    __shared__ unsigned int s[512];
    int tid = threadIdx.x;
    unsigned int v = (tid < nb) ? bcount[tid] : 0u;
    s[tid] = v; __syncthreads();
    for (int off = 1; off < 512; off <<= 1) {
        unsigned int t = (tid >= off) ? s[tid - off] : 0u;
        __syncthreads();
        s[tid] += t;
        __syncthreads();
    }
    if (tid < nb) { unsigned int ex = s[tid] - v; bstart[tid] = ex; cursor[tid] = ex; }
}

// tiled multisplit: pack (row&255)<<17 | col into per-bucket contiguous runs
__global__ void k_bscatter(const int* __restrict__ row, const int* __restrict__ col,
                           unsigned int* __restrict__ cursor,
                           unsigned int* __restrict__ binned, int E) {
    __shared__ unsigned int lcnt[NBUCK];
    __shared__ unsigned int ldst[NBUCK];
    __shared__ unsigned int lpos[NBUCK];
    int tid = threadIdx.x;
    int base = blockIdx.x * TILE;
    for (int i = tid; i < NBUCK; i += TPB) { lcnt[i] = 0u; lpos[i] = 0u; }
    __syncthreads();
    #pragma unroll 4
    for (int j = 0; j < EPT; ++j) {
        int e = base + j * TPB + tid;
        if (e < E) atomicAdd(&lcnt[((unsigned int)row[e]) >> 8], 1u);
    }
    __syncthreads();
    for (int i = tid; i < NBUCK; i += TPB) {
        unsigned int c = lcnt[i];
        ldst[i] = c ? atomicAdd(&cursor[i], c) : 0u;
    }
    __syncthreads();
    #pragma unroll 4
    for (int j = 0; j < EPT; ++j) {
        int e = base + j * TPB + tid;
        if (e < E) {
            unsigned int r = (unsigned int)row[e];
            unsigned int c = (unsigned int)col[e];
            unsigned int b = r >> 8;
            unsigned int rank = atomicAdd(&lpos[b], 1u);
            binned[ldst[b] + rank] = ((r & 255u) << 17) | c;
        }
    }
}

// one block per bucket: LDS-accumulate sum_q[col] + counts, finalize, reduce to out
__global__ void k_bucket(const float4* __restrict__ q4, const unsigned int* __restrict__ binned,
                         const unsigned int* __restrict__ bstart, const unsigned int* __restrict__ bcount,
                         float* __restrict__ out, int N) {
    __shared__ float sums[256][17];   // stride 17: avoids 32-way bank conflicts
    __shared__ unsigned int ncnt[256];
    __shared__ float wsum[4];
    int tid = threadIdx.x;
    int b = blockIdx.x;
    #pragma unroll
    for (int k = 0; k < 17; ++k) sums[tid][k] = 0.f;
    ncnt[tid] = 0u;
    __syncthreads();
    unsigned int start = bstart[b], m = bcount[b];
    for (unsigned int i = tid; i < m; i += 256u) {
        unsigned int v = binned[start + i];
        unsigned int c = v & 0x1FFFFu;
        unsigned int rl = v >> 17;
        const float4* qp = q4 + (size_t)c * 4;
        float4 a0 = qp[0], a1 = qp[1], a2 = qp[2], a3 = qp[3];
        float* s = sums[rl];
        atomicAdd(s + 0,  a0.x); atomicAdd(s + 1,  a0.y); atomicAdd(s + 2,  a0.z); atomicAdd(s + 3,  a0.w);
        atomicAdd(s + 4,  a1.x); atomicAdd(s + 5,  a1.y); atomicAdd(s + 6,  a1.z); atomicAdd(s + 7,  a1.w);
        atomicAdd(s + 8,  a2.x); atomicAdd(s + 9,  a2.y); atomicAdd(s + 10, a2.z); atomicAdd(s + 11, a2.w);
        atomicAdd(s + 12, a3.x); atomicAdd(s + 13, a3.y); atomicAdd(s + 14, a3.z); atomicAdd(s + 15, a3.w);
        atomicAdd(&ncnt[rl], 1u);
    }
    __syncthreads();
    int n = (b << 8) + tid;
    float ss = 0.f;
    if (n < N) {
        unsigned int cu = ncnt[tid];
        float cf = (float)cu;
        const float4* qp = q4 + (size_t)n * 4;
        const float* s = sums[tid];
        #pragma unroll
        for (int k = 0; k < 4; ++k) {
            float4 qv = qp[k];
            float dx = cf * qv.x - s[k * 4 + 0];
            float dy = cf * qv.y - s[k * 4 + 1];
            float dz = cf * qv.z - s[k * 4 + 2];
            float dw = cf * qv.w - s[k * 4 + 3];
            ss += dx * dx + dy * dy + dz * dz + dw * dw;
        }
        float c1 = (cu > 1u) ? cf : 1.f;
        ss /= (c1 * c1);
    }
    #pragma unroll
    for (int mm = 1; mm < 64; mm <<= 1) ss += __shfl_xor(ss, mm);
    if ((tid & 63) == 0) wsum[tid >> 6] = ss;
    __syncthreads();
    if (tid == 0)
        atomicAdd(out, (wsum[0] + wsum[1] + wsum[2] + wsum[3]) * (1.0f / (float)NN));
}

extern "C" void kernel_launch(void* const* d_in, const int* in_sizes, int n_in,
                              void* d_out, int out_size, void* d_ws, size_t ws_size,
                              hipStream_t stream) {
    const float* pred = (const float*)d_in[0];
    const float* inp  = (const float*)d_in[1];
    const int*   eidx = (const int*)d_in[2];

    const int N = NN;
    const int E = in_sizes[2] / 2;
    const int* row = eidx;
    const int* col = eidx + E;

    // ws layout
    size_t off = 0;
    auto alloc = [&](size_t bytes) { void* p = (char*)d_ws + off; off = (off + bytes + 511) & ~(size_t)511; return p; };
    float4*       q4     = (float4*)alloc((size_t)N * 16 * sizeof(float));
    unsigned int* bcount = (unsigned int*)alloc(NBUCK * sizeof(unsigned int));
    unsigned int* bstart = (unsigned int*)alloc(NBUCK * sizeof(unsigned int));
    unsigned int* cursor = (unsigned int*)alloc(NBUCK * sizeof(unsigned int));
    unsigned int* binned = (unsigned int*)alloc((size_t)E * sizeof(unsigned int));

    hipMemsetAsync(bcount, 0, NBUCK * sizeof(unsigned int), stream);
    hipMemsetAsync(d_out, 0, sizeof(float), stream);

    int n4 = N * DF / 4;
    k_q<<<(n4 + 255) / 256, 256, 0, stream>>>((const float4*)pred, (const float4*)inp, q4, n4);

    k_bhist<<<384, 256, 0, stream>>>(row, bcount, E);
    k_bscan<<<1, 512, 0, stream>>>(bcount, bstart, cursor, NBUCK);

    int nsc = (E + TILE - 1) / TILE;
    k_bscatter<<<nsc, TPB, 0, stream>>>(row, col, cursor, binned, E);

    k_bucket<<<NBUCK, 256, 0, stream>>>(q4, binned, bstart, bcount, (float*)d_out, N);
}

// Round 4
// 150.547 us; speedup vs baseline: 5.2720x; 2.7910x over previous
//
#include <hip/hip_runtime.h>

#define NN 100000
#define DF 16
#define BSH 6                      // 64 nodes per bucket
#define BNODES 64
#define NBUCK ((NN + BNODES - 1) / BNODES)   // 1563
#define TPB 256
#define EPT 64
#define TILE (TPB*EPT)             // 16384
#define MAXB 4096                  // max edges per bucket (avg ~2048)

// q = pred - input (float4 over N*16)
__global__ void k_q(const float4* __restrict__ pred, const float4* __restrict__ inp,
                    float4* __restrict__ q, int n4) {
    int i = blockIdx.x * blockDim.x + threadIdx.x;
    if (i < n4) {
        float4 a = pred[i], b = inp[i];
        float4 r; r.x = a.x - b.x; r.y = a.y - b.y; r.z = a.z - b.z; r.w = a.w - b.w;
        q[i] = r;
    }
}

// LDS-aggregated histogram of bucket = row >> BSH
__global__ void k_bhist(const int* __restrict__ row, unsigned int* __restrict__ bcount, int E) {
    __shared__ unsigned int h[NBUCK];
    for (int i = threadIdx.x; i < NBUCK; i += blockDim.x) h[i] = 0u;
    __syncthreads();
    int stride = gridDim.x * blockDim.x;
    for (int e = blockIdx.x * blockDim.x + threadIdx.x; e < E; e += stride)
        atomicAdd(&h[((unsigned int)row[e]) >> BSH], 1u);
    __syncthreads();
    for (int i = threadIdx.x; i < NBUCK; i += blockDim.x) {
        unsigned int v = h[i];
        if (v) atomicAdd(&bcount[i], v);
    }
}

// single-block exclusive scan of NBUCK (<=2048) bucket counts -> bstart, cursor
__global__ void k_bscan(const unsigned int* __restrict__ bcount,
                        unsigned int* __restrict__ bstart,
                        unsigned int* __restrict__ cursor, int nb) {
    __shared__ unsigned int s[512];
    int tid = threadIdx.x;
    unsigned int v[4]; unsigned int sum = 0u;
    #pragma unroll
    for (int j = 0; j < 4; ++j) {
        int idx = tid * 4 + j;
        v[j] = (idx < nb) ? bcount[idx] : 0u;
        sum += v[j];
    }
    s[tid] = sum; __syncthreads();
    for (int off = 1; off < 512; off <<= 1) {
        unsigned int t = (tid >= off) ? s[tid - off] : 0u;
        __syncthreads();
        s[tid] += t;
        __syncthreads();
    }
    unsigned int ex = s[tid] - sum;
    #pragma unroll
    for (int j = 0; j < 4; ++j) {
        int idx = tid * 4 + j;
        if (idx < nb) { bstart[idx] = ex; cursor[idx] = ex; }
        ex += v[j];
    }
}

// tiled multisplit: pack (row&63)<<17 | col into per-bucket contiguous runs
__global__ void k_bscatter(const int* __restrict__ row, const int* __restrict__ col,
                           unsigned int* __restrict__ cursor,
                           unsigned int* __restrict__ binned, int E) {
    __shared__ unsigned int lcnt[NBUCK];
    __shared__ unsigned int ldst[NBUCK];
    __shared__ unsigned int lpos[NBUCK];
    int tid = threadIdx.x;
    long long base = (long long)blockIdx.x * TILE;
    for (int i = tid; i < NBUCK; i += TPB) { lcnt[i] = 0u; lpos[i] = 0u; }
    __syncthreads();
    for (int j = 0; j < EPT; ++j) {
        long long e = base + j * TPB + tid;
        if (e < E) atomicAdd(&lcnt[((unsigned int)row[e]) >> BSH], 1u);
    }
    __syncthreads();
    for (int i = tid; i < NBUCK; i += TPB) {
        unsigned int c = lcnt[i];
        ldst[i] = c ? atomicAdd(&cursor[i], c) : 0u;
    }
    __syncthreads();
    for (int j = 0; j < EPT; ++j) {
        long long e = base + j * TPB + tid;
        if (e < E) {
            unsigned int r = (unsigned int)row[e];
            unsigned int c = (unsigned int)col[e];
            unsigned int b = r >> BSH;
            unsigned int rank = atomicAdd(&lpos[b], 1u);
            binned[ldst[b] + rank] = ((r & (BNODES - 1u)) << 17) | c;
        }
    }
}

// one block per 64-node bucket: LDS counting-sort edges by local node, then
// register-accumulate per node (1 wave per node, 16 edge slots x 4 feat-lanes),
// finalize ||cnt*q - sum||^2 / max(cnt,1)^2 and reduce into out.
__global__ void k_bucket(const float4* __restrict__ q4, const unsigned int* __restrict__ binned,
                         const unsigned int* __restrict__ bstart, const unsigned int* __restrict__ bcount,
                         float* __restrict__ out, int N) {
    __shared__ unsigned int ncnt[BNODES];
    __shared__ unsigned int nstart[BNODES];
    __shared__ unsigned int ncur[BNODES];
    __shared__ int scol[MAXB];
    __shared__ float wred[4];
    int tid = threadIdx.x;
    int b = blockIdx.x;
    if (tid < BNODES) ncnt[tid] = 0u;
    __syncthreads();
    unsigned int start = bstart[b], m = bcount[b];
    for (unsigned int i = tid; i < m; i += (unsigned int)TPB)
        atomicAdd(&ncnt[binned[start + i] >> 17], 1u);
    __syncthreads();
    if (tid < BNODES) {   // wave 0: exclusive scan of 64 counts via shfl
        unsigned int vv = ncnt[tid];
        unsigned int x = vv;
        #pragma unroll
        for (int off = 1; off < 64; off <<= 1) {
            unsigned int t = __shfl_up(x, off);
            if ((tid & 63) >= off) x += t;
        }
        nstart[tid] = x - vv;
        ncur[tid]   = x - vv;
    }
    __syncthreads();
    for (unsigned int i = tid; i < m; i += (unsigned int)TPB) {
        unsigned int v = binned[start + i];
        unsigned int rl = v >> 17;
        unsigned int rank = atomicAdd(&ncur[rl], 1u);
        if (rank < MAXB) scol[rank] = (int)(v & 0x1FFFFu);
    }
    __syncthreads();

    int wid = tid >> 6;
    int lane = tid & 63;
    int slot = lane >> 2;   // 0..15 edge slot
    int p = lane & 3;       // feature quad
    float bss = 0.f;
    for (int nl = wid; nl < BNODES; nl += 4) {
        int n = (b << BSH) + nl;
        unsigned int cnt = ncnt[nl];
        unsigned int st = nstart[nl];
        if (st + cnt > MAXB) cnt = (st < MAXB) ? (MAXB - st) : 0u;  // never triggers; safety
        float4 acc = make_float4(0.f, 0.f, 0.f, 0.f);
        for (unsigned int basee = 0; basee < cnt; basee += 16u) {
            unsigned int idx = basee + (unsigned int)slot;
            if (idx < cnt) {
                int c = scol[st + idx];
                float4 v = q4[(size_t)c * 4 + p];
                acc.x += v.x; acc.y += v.y; acc.z += v.z; acc.w += v.w;
            }
        }
        #pragma unroll
        for (int mm = 4; mm < 64; mm <<= 1) {
            acc.x += __shfl_xor(acc.x, mm);
            acc.y += __shfl_xor(acc.y, mm);
            acc.z += __shfl_xor(acc.z, mm);
            acc.w += __shfl_xor(acc.w, mm);
        }
        float ss = 0.f;
        if (n < N) {
            float4 qn = q4[(size_t)n * 4 + p];
            float cf = (float)cnt;
            float sx = cf * qn.x - acc.x;
            float sy = cf * qn.y - acc.y;
            float sz = cf * qn.z - acc.z;
            float sw = cf * qn.w - acc.w;
            ss = sx * sx + sy * sy + sz * sz + sw * sw;
        }
        ss += __shfl_xor(ss, 1);
        ss += __shfl_xor(ss, 2);
        if (lane == 0 && n < N) {
            float c1 = (cnt > 1u) ? (float)cnt : 1.f;
            bss += ss / (c1 * c1);
        }
    }
    if (lane == 0) wred[wid] = bss;
    __syncthreads();
    if (tid == 0)
        atomicAdd(out, (wred[0] + wred[1] + wred[2] + wred[3]) * (1.0f / (float)NN));
}

extern "C" void kernel_launch(void* const* d_in, const int* in_sizes, int n_in,
                              void* d_out, int out_size, void* d_ws, size_t ws_size,
                              hipStream_t stream) {
    const float* pred = (const float*)d_in[0];
    const float* inp  = (const float*)d_in[1];
    const int*   eidx = (const int*)d_in[2];

    const int N = NN;
    const int E = in_sizes[2] / 2;
    const int* row = eidx;
    const int* col = eidx + E;

    // ws layout
    size_t off = 0;
    auto alloc = [&](size_t bytes) { void* p = (char*)d_ws + off; off = (off + bytes + 511) & ~(size_t)511; return p; };
    float4*       q4     = (float4*)alloc((size_t)N * 16 * sizeof(float));
    unsigned int* bcount = (unsigned int*)alloc(NBUCK * sizeof(unsigned int));
    unsigned int* bstart = (unsigned int*)alloc(NBUCK * sizeof(unsigned int));
    unsigned int* cursor = (unsigned int*)alloc(NBUCK * sizeof(unsigned int));
    unsigned int* binned = (unsigned int*)alloc((size_t)E * sizeof(unsigned int));

    hipMemsetAsync(bcount, 0, NBUCK * sizeof(unsigned int), stream);
    hipMemsetAsync(d_out, 0, sizeof(float), stream);

    int n4 = N * DF / 4;
    k_q<<<(n4 + 255) / 256, 256, 0, stream>>>((const float4*)pred, (const float4*)inp, q4, n4);

    k_bhist<<<256, 256, 0, stream>>>(row, bcount, E);
    k_bscan<<<1, 512, 0, stream>>>(bcount, bstart, cursor, NBUCK);

    int nsc = (E + TILE - 1) / TILE;
    k_bscatter<<<nsc, TPB, 0, stream>>>(row, col, cursor, binned, E);

    k_bucket<<<NBUCK, 256, 0, stream>>>(q4, binned, bstart, bcount, (float*)d_out, N);
}